// Round 2
// baseline (206.173 us; speedup 1.0000x reference)
//
#include <hip/hip_runtime.h>
#include <math.h>

#define HID 128
#define NEXP 8
#define NGRAPH 64
#define EPC 2048       // edges per chunk: 782 chunks -> ~3 blocks/CU (was 261 = 1/CU)
#define EPT 8          // edges per thread (EPC/256)
#define MAXB 512       // max coarse buckets (n <= 131072)
#define NXC 8          // XCD classes (blockIdx&7 heuristic)
#define NREP 8         // pool replicas (atomic-contention spreading)
#define NPS 8          // nodes per 16-lane slot in k_gz
#define HALF 128       // fine ids per k_binB block
#define STAGE_CAP 4096 // LDS stage for one (bucket,half): mean ~2046, sigma ~45

__device__ inline unsigned short f2bf(float f) {
    unsigned u = __float_as_uint(f);
    u += 0x7FFF + ((u >> 16) & 1);          // RNE
    return (unsigned short)(u >> 16);
}
__device__ inline unsigned packbf(float lo, float hi) {
    return (unsigned)f2bf(lo) | ((unsigned)f2bf(hi) << 16);
}
__device__ inline float bflo(unsigned u) { return __uint_as_float(u << 16); }
__device__ inline float bfhi(unsigned u) { return __uint_as_float(u & 0xFFFF0000u); }

// ---------------- init: pool/pcnt zero, gcur8 = region bases, ticket, C, bb2 ---
__global__ void k_init0(float* __restrict__ pool, float* __restrict__ pcnt,
                        const float* __restrict__ W2, const float* __restrict__ Wlin,
                        const float* __restrict__ b2, float* __restrict__ C,
                        float* __restrict__ bb2, int* __restrict__ gcur8,
                        int mregions, int capx) {
    int i = blockIdx.x * 256 + threadIdx.x;
    if (i < mregions) gcur8[i] = i * capx;
    if (i == mregions) gcur8[i] = 0;         // ticket for fused log-softmax
    if (i < NREP * NGRAPH * NEXP) pool[i] = 0.0f;
    if (i < NREP * NGRAPH) pcnt[i] = 0.0f;
    int ci = i - NREP * NGRAPH * NEXP;
    if (ci >= 0 && ci < HID * NEXP) {        // C[k][j] = sum_m W2[k][m]*Wlin[m][j]
        int k = ci >> 3, j = ci & 7;
        float s = 0.0f;
        for (int m = 0; m < HID; m++) s += W2[k * HID + m] * Wlin[m * NEXP + j];
        C[ci] = s;
    }
    int bi = ci - HID * NEXP;
    if (bi >= 0 && bi < NEXP) {              // bb2[j] = sum_m b2[m]*Wlin[m][j]
        float s = 0.0f;
        for (int m = 0; m < HID; m++) s += b2[m] * Wlin[m * NEXP + bi];
        bb2[bi] = s;
    }
}

// ---------------- pass A: LDS counting-sort binning into fixed regions ---------
// 8 edges/thread via int4 loads; dual LDS histograms; shfl scan; sorted
// write-out. EPC=2048 -> 782 blocks (~3/CU) for latency hiding; write runs
// shorten to ~5.2 edges (small partial-line cost traded for occupancy).
__global__ void __launch_bounds__(256) k_binA(
        const int* __restrict__ src, const int* __restrict__ dst,
        int* __restrict__ gcur8, unsigned* __restrict__ binned, int e, int nbuck) {
    __shared__ int h0[MAXB];
    __shared__ int h1[MAXB];
    __shared__ int lstart[MAXB];
    __shared__ int lcur[MAXB];
    __shared__ int gbase[MAXB];
    __shared__ int wtot[4];
    __shared__ unsigned packed[EPC];
    __shared__ unsigned short sbkt[EPC];
    int c = blockIdx.x, t = threadIdx.x;
    int w = t >> 6, lane = t & 63;
    int x = c & (NXC - 1);
    int start = c * EPC;
    int m = e - start < EPC ? e - start : EPC;

    int d[EPT], sv[EPT];
    if (m == EPC) {
        const int4* d4 = (const int4*)(dst + start);
        const int4* s4 = (const int4*)(src + start);
#pragma unroll
        for (int q = 0; q < EPT / 4; q++) {
            int4 dd4 = d4[(EPT / 4) * t + q];
            int4 ss4 = s4[(EPT / 4) * t + q];
            d[4 * q + 0] = dd4.x; d[4 * q + 1] = dd4.y;
            d[4 * q + 2] = dd4.z; d[4 * q + 3] = dd4.w;
            sv[4 * q + 0] = ss4.x; sv[4 * q + 1] = ss4.y;
            sv[4 * q + 2] = ss4.z; sv[4 * q + 3] = ss4.w;
        }
    } else {
#pragma unroll
        for (int j = 0; j < EPT; j++) {
            int idx = t * EPT + j;
            if (idx < m) { d[j] = dst[start + idx]; sv[j] = src[start + idx]; }
        }
    }
    int* hm = (w < 2) ? h0 : h1;
    h0[t] = 0; h0[t + 256] = 0;
    h1[t] = 0; h1[t + 256] = 0;
    __syncthreads();
#pragma unroll
    for (int j = 0; j < EPT; j++)
        if (t * EPT + j < m) atomicAdd(&hm[d[j] >> 8], 1);
    __syncthreads();
    // shfl-based exclusive scan of 512 counters (2 per thread)
    int v0 = h0[2 * t] + h1[2 * t];
    int v1 = h0[2 * t + 1] + h1[2 * t + 1];
    int sum = v0 + v1;
    int incl = sum;
#pragma unroll
    for (int dd = 1; dd < 64; dd <<= 1) {
        int y = __shfl_up(incl, dd, 64);
        if (lane >= dd) incl += y;
    }
    if (lane == 63) wtot[w] = incl;
    __syncthreads();
    int pre = 0;
#pragma unroll
    for (int ww = 0; ww < 4; ww++) pre += (ww < w) ? wtot[ww] : 0;
    int ex = pre + incl - sum;
    lstart[2 * t] = ex;     lstart[2 * t + 1] = ex + v0;
    lcur[2 * t]   = ex;     lcur[2 * t + 1]   = ex + v0;
    // global range reservation per touched bucket (fixed-capacity regions)
    for (int b = t; b < nbuck; b += 256) {
        int hv = h0[b] + h1[b];
        gbase[b] = hv ? atomicAdd(&gcur8[b * NXC + x], hv) : 0;
    }
    __syncthreads();
    // LDS sort (scatter to dense local ranks)
#pragma unroll
    for (int j = 0; j < EPT; j++) {
        if (t * EPT + j < m) {
            int b = d[j] >> 8;
            int p = atomicAdd(&lcur[b], 1);
            packed[p] = ((unsigned)(d[j] & 255) << 24) | (unsigned)sv[j];
            sbkt[p] = (unsigned short)b;
        }
    }
    __syncthreads();
    // coalesced write-out: consecutive local ranks -> consecutive global slots
    for (int idx = t; idx < m; idx += 256) {
        int b = sbkt[idx];
        binned[gbase[b] + (idx - lstart[b])] = packed[idx];
    }
}

// ---------------- pass B: single global read + LDS stage + fine sort ----------
// grid = 2*nbuck; block (b,h) streams the bucket's 8 sub-regions ONCE,
// wave-ballot-compacts its half into an LDS stage buffer (histogram on the
// fly), then scans and scatters from LDS. Halves binB's global traffic and
// removes the second global-latency pass.
__global__ void k_binB(const unsigned* __restrict__ binned, const int* __restrict__ gcur8,
                       const float* __restrict__ an, const float* __restrict__ pos,
                       int* __restrict__ cnt, int* __restrict__ off,
                       float* __restrict__ dinv, float4* __restrict__ xs,
                       int* __restrict__ eidx, int n, int capx) {
    __shared__ int h[HALF];
    __shared__ int cur[HALF];
    __shared__ int wtot[2];
    __shared__ int scnt;
    __shared__ unsigned stage[STAGE_CAP];
    int bh = blockIdx.x, t = threadIdx.x;
    int b = bh >> 1, half = bh & 1;
    int cbase = b * NXC;
    int hb = cbase * capx + half * (NXC / 2) * capx;   // half's output base
    int lane = t & 63;
    if (t < HALF) h[t] = 0;
    if (t == 0) scnt = 0;
    __syncthreads();
#pragma unroll
    for (int x = 0; x < NXC; x++) {
        int rs = (cbase + x) * capx, re = gcur8[cbase + x];
        for (int k0 = rs; k0 < re; k0 += 256) {
            int k = k0 + t;
            unsigned u = 0;
            bool keep = false;
            if (k < re) {
                u = binned[k];
                keep = ((int)(u >> 24) >> 7) == half;
            }
            unsigned long long msk = __ballot(keep);
            int pre = __popcll(msk & ((1ull << lane) - 1ull));
            int cw = __popcll(msk);
            int base = 0;
            if (lane == 0 && cw) base = atomicAdd(&scnt, cw);
            base = __shfl(base, 0, 64);
            if (keep) {
                int p = base + pre;
                if (p < STAGE_CAP) stage[p] = u;
                atomicAdd(&h[(u >> 24) & (HALF - 1)], 1);
            }
        }
    }
    __syncthreads();
    // shfl exclusive scan of 128 counters (threads 0..127, 2 waves)
    int v = 0, ex = 0;
    if (t < HALF) {
        int w = t >> 6;
        v = h[t];
        int incl = v;
#pragma unroll
        for (int dd = 1; dd < 64; dd <<= 1) {
            int y = __shfl_up(incl, dd, 64);
            if (lane >= dd) incl += y;
        }
        if (lane == 63) wtot[w] = incl;
        ex = incl - v;
    }
    __syncthreads();
    if (t < HALF) {
        if (t >= 64) ex += wtot[0];
        cur[t] = ex;
        int node = (b << 8) + half * HALF + t;
        if (node < n) {
            float di = rsqrtf((float)v + 1.0f);   // +1 = self-loop
            cnt[node]  = v;
            off[node]  = hb + ex;
            dinv[node] = di;
            xs[node] = make_float4(an[node] * di, pos[3 * node] * di,
                                   pos[3 * node + 1] * di, pos[3 * node + 2] * di);
        }
    }
    __syncthreads();
    int total = scnt < STAGE_CAP ? scnt : STAGE_CAP;
    for (int k = t; k < total; k += 256) {
        unsigned u = stage[k];
        int p = atomicAdd(&cur[(u >> 24) & (HALF - 1)], 1);
        eidx[hb + p] = (int)(u & 0xFFFFFF);
    }
}

// ---------------- fused layer-1 gather + dense + z projection ------------------
// 2 threads per node: edge loop split by parity, a combined via shfl; dense
// loop redundant (weights wave-uniform -> scalar loads); even thread stores.
__global__ void k_gxz(const float4* __restrict__ xs, const int* __restrict__ eidx,
                      const int* __restrict__ off, const int* __restrict__ cnt,
                      const float* __restrict__ dinv, const float* __restrict__ W1,
                      const float* __restrict__ b1, const float* __restrict__ C,
                      uint4* __restrict__ z, int n) {
    int tid = blockIdx.x * 256 + threadIdx.x;
    int i = tid >> 1;
    int par = tid & 1;
    if (i >= n) return;
    float4 a = par ? make_float4(0.f, 0.f, 0.f, 0.f) : xs[i];   // self-loop once
    int o = off[i], c = cnt[i];
    int k = par;
    for (; k + 6 < c; k += 8) {
        int i0 = eidx[o + k],     i1 = eidx[o + k + 2];
        int i2 = eidx[o + k + 4], i3 = eidx[o + k + 6];
        float4 v0 = xs[i0], v1 = xs[i1], v2 = xs[i2], v3 = xs[i3];
        a.x += v0.x + v1.x + v2.x + v3.x;
        a.y += v0.y + v1.y + v2.y + v3.y;
        a.z += v0.z + v1.z + v2.z + v3.z;
        a.w += v0.w + v1.w + v2.w + v3.w;
    }
    for (; k < c; k += 2) {
        float4 v0 = xs[eidx[o + k]];
        a.x += v0.x; a.y += v0.y; a.z += v0.z; a.w += v0.w;
    }
    a.x += __shfl_xor(a.x, 1, 64);
    a.y += __shfl_xor(a.y, 1, 64);
    a.z += __shfl_xor(a.z, 1, 64);
    a.w += __shfl_xor(a.w, 1, 64);
    float di = dinv[i];
    float z0 = 0.f, z1 = 0.f, z2 = 0.f, z3 = 0.f,
          z4 = 0.f, z5 = 0.f, z6 = 0.f, z7 = 0.f;
#pragma unroll 4
    for (int kk = 0; kk < HID; kk++) {      // all weight indices wave-uniform
        float x1k = fmaxf(di * (a.x * W1[kk] + a.y * W1[HID + kk] +
                                a.z * W1[2 * HID + kk] + a.w * W1[3 * HID + kk])
                          + b1[kk], 0.0f);
        const float* cr = C + kk * NEXP;
        z0 += x1k * cr[0]; z1 += x1k * cr[1];
        z2 += x1k * cr[2]; z3 += x1k * cr[3];
        z4 += x1k * cr[4]; z5 += x1k * cr[5];
        z6 += x1k * cr[6]; z7 += x1k * cr[7];
    }
    if (par == 0) {
        uint4 outv;
        outv.x = packbf(z0 * di, z1 * di);
        outv.y = packbf(z2 * di, z3 * di);
        outv.z = packbf(z4 * di, z5 * di);
        outv.w = packbf(z6 * di, z7 * di);
        z[i] = outv;
    }
}

// ---------------- fused gather2 + pooling + last-block log_softmax -------------
__global__ void k_gz(const uint4* __restrict__ z4, const int* __restrict__ eidx,
                     const int* __restrict__ off, const int* __restrict__ cnt,
                     const float* __restrict__ dinv, const int* __restrict__ batch,
                     float* __restrict__ pool, float* __restrict__ pcnt,
                     const float* __restrict__ blin, const float* __restrict__ bb2,
                     float* __restrict__ out, int* __restrict__ ticket,
                     int nblk, int n) {
    int t = threadIdx.x;
    int slot = t >> 4;          // 0..15 within block
    int l = t & 15;             // lane within slot
    int i0 = blockIdx.x * (16 * NPS) + slot * NPS;
    if (i0 < n) {
        int i1 = i0 + NPS < n ? i0 + NPS : n;
        int rep = (blockIdx.x + slot) & (NREP - 1);
        float* rp  = pool + (size_t)rep * NGRAPH * NEXP;
        float* rpc = pcnt + (size_t)rep * NGRAPH;
        int Q = l >> 2;

        int curg = -1;
        float r0 = 0.0f, r1 = 0.0f, runlen = 0.0f;
        for (int i = i0; i < i1; i++) {
            float a0 = 0.f, a1 = 0.f, a2 = 0.f, a3 = 0.f,
                  a4 = 0.f, a5 = 0.f, a6 = 0.f, a7 = 0.f;
            int o = off[i], c = cnt[i];
            for (int k = l; k < c; k += 16) {
                uint4 zr = z4[eidx[o + k]];
                a0 += bflo(zr.x); a1 += bfhi(zr.x);
                a2 += bflo(zr.y); a3 += bfhi(zr.y);
                a4 += bflo(zr.z); a5 += bfhi(zr.z);
                a6 += bflo(zr.w); a7 += bfhi(zr.w);
            }
            if (l == 0) {                        // self-loop once
                uint4 zr = z4[i];
                a0 += bflo(zr.x); a1 += bfhi(zr.x);
                a2 += bflo(zr.y); a3 += bfhi(zr.y);
                a4 += bflo(zr.z); a5 += bfhi(zr.z);
                a6 += bflo(zr.w); a7 += bfhi(zr.w);
            }
            a0 += __shfl_xor(a0, 8, 64); a1 += __shfl_xor(a1, 8, 64);
            a2 += __shfl_xor(a2, 8, 64); a3 += __shfl_xor(a3, 8, 64);
            a4 += __shfl_xor(a4, 8, 64); a5 += __shfl_xor(a5, 8, 64);
            a6 += __shfl_xor(a6, 8, 64); a7 += __shfl_xor(a7, 8, 64);
            a0 += __shfl_xor(a0, 4, 64); a1 += __shfl_xor(a1, 4, 64);
            a2 += __shfl_xor(a2, 4, 64); a3 += __shfl_xor(a3, 4, 64);
            a4 += __shfl_xor(a4, 4, 64); a5 += __shfl_xor(a5, 4, 64);
            a6 += __shfl_xor(a6, 4, 64); a7 += __shfl_xor(a7, 4, 64);
            float r0v, r1v;
            switch (Q) {
                case 0:  r0v = a0; r1v = a1; break;
                case 1:  r0v = a2; r1v = a3; break;
                case 2:  r0v = a4; r1v = a5; break;
                default: r0v = a6; r1v = a7; break;
            }
            r0v += __shfl_xor(r0v, 1, 64); r1v += __shfl_xor(r1v, 1, 64);
            r0v += __shfl_xor(r0v, 2, 64); r1v += __shfl_xor(r1v, 2, 64);
            float di = dinv[i];
            float v0 = di * r0v, v1 = di * r1v;
            int g = batch[i];
            if (g != curg) {                     // slot-uniform branch
                if (curg >= 0 && (l & 3) == 0) {
                    atomicAdd(&rp[curg * NEXP + 2 * Q], r0);
                    atomicAdd(&rp[curg * NEXP + 2 * Q + 1], r1);
                    if (l == 0) atomicAdd(&rpc[curg], runlen);
                }
                curg = g; r0 = v0; r1 = v1; runlen = 1.0f;
            } else { r0 += v0; r1 += v1; runlen += 1.0f; }
        }
        if (curg >= 0 && (l & 3) == 0) {
            atomicAdd(&rp[curg * NEXP + 2 * Q], r0);
            atomicAdd(&rp[curg * NEXP + 2 * Q + 1], r1);
            if (l == 0) atomicAdd(&rpc[curg], runlen);
        }
    }
    // ---- last-block fused log_softmax (device-scope ticket) ----
    __shared__ int lastFlag;
    __syncthreads();                 // drains this block's atomics (vmcnt(0))
    if (t == 0) {
        __threadfence();
        lastFlag = (atomicAdd(ticket, 1) == nblk - 1);
    }
    __syncthreads();
    if (lastFlag && t < NGRAPH) {
        int g = t;
        float p[NEXP];
#pragma unroll
        for (int k = 0; k < NEXP; k++) p[k] = 0.0f;
        float cg = 0.0f;
#pragma unroll
        for (int rr = 0; rr < NREP; rr++) {
#pragma unroll
            for (int k = 0; k < NEXP; k++)
                p[k] += atomicAdd(&pool[rr * NGRAPH * NEXP + g * NEXP + k], 0.0f);
            cg += atomicAdd(&pcnt[rr * NGRAPH + g], 0.0f);
        }
        float inv = 1.0f / fmaxf(cg, 1.0f);
        float v[NEXP], m = -1e30f;
#pragma unroll
        for (int k = 0; k < NEXP; k++) {
            v[k] = p[k] * inv + blin[k] + bb2[k];
            m = fmaxf(m, v[k]);
        }
        float s = 0.0f;
#pragma unroll
        for (int k = 0; k < NEXP; k++) s += expf(v[k] - m);
        float ls = logf(s);
#pragma unroll
        for (int k = 0; k < NEXP; k++) out[g * NEXP + k] = v[k] - m - ls;
    }
}

extern "C" void kernel_launch(void* const* d_in, const int* in_sizes, int n_in,
                              void* d_out, int out_size, void* d_ws, size_t ws_size,
                              hipStream_t stream) {
    const float* an   = (const float*)d_in[0];
    const float* pos  = (const float*)d_in[1];
    const int*   ei   = (const int*)d_in[2];     // [2, E] flat (int32 view)
    const int*   batch= (const int*)d_in[3];
    const float* W1   = (const float*)d_in[4];
    const float* b1   = (const float*)d_in[5];
    const float* W2   = (const float*)d_in[6];
    const float* b2   = (const float*)d_in[7];
    const float* Wlin = (const float*)d_in[8];
    const float* blin = (const float*)d_in[9];
    float* out = (float*)d_out;

    const int n = in_sizes[0];
    const int e = in_sizes[2] / 2;
    const int* src = ei;
    const int* dst = ei + e;

    const int nbuck = (n + 255) >> 8;            // coarse buckets (<= MAXB)
    const int ch    = (e + EPC - 1) / EPC;       // chunks
    const int mreg  = nbuck * NXC;               // fixed-capacity regions
    const int capx  = 2 * (e / (mreg > 0 ? mreg : 1)) + 256;   // ~34 sigma slack

    // workspace layout (16B-aligned buffers first)
    char* p = (char*)d_ws;
    float4* xs    = (float4*)p;       p += sizeof(float4) * (size_t)n;
    uint4*  z     = (uint4*)p;        p += sizeof(uint4) * (size_t)n;   // bf16[8]/node
    float* C      = (float*)p;        p += sizeof(float) * HID * NEXP;
    float* bb2    = (float*)p;        p += sizeof(float) * NEXP;
    float* dinv   = (float*)p;        p += sizeof(float) * (size_t)n;
    float* pool   = (float*)p;        p += sizeof(float) * NREP * NGRAPH * NEXP;
    float* pcnt   = (float*)p;        p += sizeof(float) * NREP * NGRAPH;
    int*   cnt    = (int*)p;          p += sizeof(int) * (size_t)n;
    int*   off    = (int*)p;          p += sizeof(int) * (size_t)n;
    int*   gcur8  = (int*)p;          p += sizeof(int) * (mreg + 8);
    unsigned* binned = (unsigned*)p;  p += sizeof(unsigned) * (size_t)mreg * capx;
    int*   eidx   = (int*)p;          p += sizeof(int) * (size_t)mreg * capx;
    int*   ticket = gcur8 + mreg;                // zeroed by k_init0

    // init (region bases replace hist+cscan) + binning + fine sort
    const int initN = NREP * NGRAPH * NEXP + HID * NEXP + NEXP;
    const int initG = initN > mreg + 1 ? initN : mreg + 1;
    k_init0<<<(initG + 255) / 256, 256, 0, stream>>>(pool, pcnt, W2, Wlin, b2, C,
                                                     bb2, gcur8, mreg, capx);
    k_binA<<<ch, 256, 0, stream>>>(src, dst, gcur8, binned, e, nbuck);
    k_binB<<<2 * nbuck, 256, 0, stream>>>(binned, gcur8, an, pos, cnt, off, dinv,
                                          xs, eidx, n, capx);

    // fused layer-1 gather + dense + projection to z (2 threads/node)
    k_gxz<<<(2 * n + 255) / 256, 256, 0, stream>>>(xs, eidx, off, cnt, dinv,
                                                   W1, b1, C, z, n);

    // layer 2 gather in 8-dim z-space + pooling + fused log_softmax
    const int nblk = (n + 16 * NPS - 1) / (16 * NPS);
    k_gz<<<nblk, 256, 0, stream>>>(z, eidx, off, cnt, dinv, batch, pool, pcnt,
                                   blin, bb2, out, ticket, nblk, n);
}

// Round 3
// 174.880 us; speedup vs baseline: 1.1789x; 1.1789x over previous
//
#include <hip/hip_runtime.h>
#include <math.h>

#define HID 128
#define NEXP 8
#define NGRAPH 64
#define EPC 6144       // edges per chunk: run len ~15.7 -> write txns near full-line floor
#define MAXB 512       // max coarse buckets (n <= 131072)
#define NXC 8          // XCD classes (blockIdx&7 heuristic)
#define NREP 8         // pool replicas (atomic-contention spreading)
#define NPS 8          // nodes per 16-lane slot in k_gz
#define HALF 128       // fine ids per k_binB block
#define STAGE_CAP 4096 // LDS stage for one (bucket,half): mean ~2048, sigma ~45

__device__ inline unsigned short f2bf(float f) {
    unsigned u = __float_as_uint(f);
    u += 0x7FFF + ((u >> 16) & 1);          // RNE
    return (unsigned short)(u >> 16);
}
__device__ inline unsigned packbf(float lo, float hi) {
    return (unsigned)f2bf(lo) | ((unsigned)f2bf(hi) << 16);
}
__device__ inline float bflo(unsigned u) { return __uint_as_float(u << 16); }
__device__ inline float bfhi(unsigned u) { return __uint_as_float(u & 0xFFFF0000u); }

// ---------------- init: pool/pcnt zero, gcur8 = region bases, C, bb2 -----------
__global__ void k_init0(float* __restrict__ pool, float* __restrict__ pcnt,
                        const float* __restrict__ W2, const float* __restrict__ Wlin,
                        const float* __restrict__ b2, float* __restrict__ C,
                        float* __restrict__ bb2, int* __restrict__ gcur8,
                        int mregions, int capx) {
    int i = blockIdx.x * 256 + threadIdx.x;
    if (i < mregions) gcur8[i] = i * capx;
    if (i < NREP * NGRAPH * NEXP) pool[i] = 0.0f;
    if (i < NREP * NGRAPH) pcnt[i] = 0.0f;
    int ci = i - NREP * NGRAPH * NEXP;
    if (ci >= 0 && ci < HID * NEXP) {        // C[k][j] = sum_m W2[k][m]*Wlin[m][j]
        int k = ci >> 3, j = ci & 7;
        float s = 0.0f;
        for (int m = 0; m < HID; m++) s += W2[k * HID + m] * Wlin[m * NEXP + j];
        C[ci] = s;
    }
    int bi = ci - HID * NEXP;
    if (bi >= 0 && bi < NEXP) {              // bb2[j] = sum_m b2[m]*Wlin[m][j]
        float s = 0.0f;
        for (int m = 0; m < HID; m++) s += b2[m] * Wlin[m * NEXP + bi];
        bb2[bi] = s;
    }
}

// ---------------- pass A: LDS counting-sort binning into fixed regions ---------
// 24 edges/thread via int4 loads; dual LDS histograms; shfl scan; sorted
// write-out in ~15.7-edge runs (write transactions near full-line floor).
__global__ void __launch_bounds__(256) k_binA(
        const int* __restrict__ src, const int* __restrict__ dst,
        int* __restrict__ gcur8, unsigned* __restrict__ binned, int e, int nbuck) {
    __shared__ int h0[MAXB];
    __shared__ int h1[MAXB];
    __shared__ int lstart[MAXB];
    __shared__ int lcur[MAXB];
    __shared__ int gbase[MAXB];
    __shared__ int wtot[4];
    __shared__ unsigned packed[EPC];
    __shared__ unsigned short sbkt[EPC];
    int c = blockIdx.x, t = threadIdx.x;
    int w = t >> 6, lane = t & 63;
    int x = c & (NXC - 1);
    int start = c * EPC;
    int m = e - start < EPC ? e - start : EPC;

    int d[24], sv[24];
    if (m == EPC) {
        const int4* d4 = (const int4*)(dst + start);
        const int4* s4 = (const int4*)(src + start);
#pragma unroll
        for (int q = 0; q < 6; q++) {
            int4 dd4 = d4[6 * t + q];
            int4 ss4 = s4[6 * t + q];
            d[4 * q + 0] = dd4.x; d[4 * q + 1] = dd4.y;
            d[4 * q + 2] = dd4.z; d[4 * q + 3] = dd4.w;
            sv[4 * q + 0] = ss4.x; sv[4 * q + 1] = ss4.y;
            sv[4 * q + 2] = ss4.z; sv[4 * q + 3] = ss4.w;
        }
    } else {
#pragma unroll
        for (int j = 0; j < 24; j++) {
            int idx = t * 24 + j;
            if (idx < m) { d[j] = dst[start + idx]; sv[j] = src[start + idx]; }
        }
    }
    int* hm = (w < 2) ? h0 : h1;
    h0[t] = 0; h0[t + 256] = 0;
    h1[t] = 0; h1[t + 256] = 0;
    __syncthreads();
#pragma unroll
    for (int j = 0; j < 24; j++)
        if (t * 24 + j < m) atomicAdd(&hm[d[j] >> 8], 1);
    __syncthreads();
    // shfl-based exclusive scan of 512 counters (2 per thread)
    int v0 = h0[2 * t] + h1[2 * t];
    int v1 = h0[2 * t + 1] + h1[2 * t + 1];
    int sum = v0 + v1;
    int incl = sum;
#pragma unroll
    for (int dd = 1; dd < 64; dd <<= 1) {
        int y = __shfl_up(incl, dd, 64);
        if (lane >= dd) incl += y;
    }
    if (lane == 63) wtot[w] = incl;
    __syncthreads();
    int pre = 0;
#pragma unroll
    for (int ww = 0; ww < 4; ww++) pre += (ww < w) ? wtot[ww] : 0;
    int ex = pre + incl - sum;
    lstart[2 * t] = ex;     lstart[2 * t + 1] = ex + v0;
    lcur[2 * t]   = ex;     lcur[2 * t + 1]   = ex + v0;
    // global range reservation per touched bucket (fixed-capacity regions)
    for (int b = t; b < nbuck; b += 256) {
        int hv = h0[b] + h1[b];
        gbase[b] = hv ? atomicAdd(&gcur8[b * NXC + x], hv) : 0;
    }
    __syncthreads();
    // LDS sort (scatter to dense local ranks)
#pragma unroll
    for (int j = 0; j < 24; j++) {
        if (t * 24 + j < m) {
            int b = d[j] >> 8;
            int p = atomicAdd(&lcur[b], 1);
            packed[p] = ((unsigned)(d[j] & 255) << 24) | (unsigned)sv[j];
            sbkt[p] = (unsigned short)b;
        }
    }
    __syncthreads();
    // coalesced write-out: consecutive local ranks -> consecutive global slots
    for (int idx = t; idx < m; idx += 256) {
        int b = sbkt[idx];
        binned[gbase[b] + (idx - lstart[b])] = packed[idx];
    }
}

// ---------------- pass B: single global read + LDS stage + fine sort ----------
// grid = 2*nbuck; block (b,h) streams the bucket's 8 sub-regions ONCE,
// wave-ballot-compacts its half into an LDS stage buffer (histogram on the
// fly), then scans and scatters from LDS. Halves binB's global traffic and
// removes the second full-latency streaming pass.
__global__ void k_binB(const unsigned* __restrict__ binned, const int* __restrict__ gcur8,
                       const float* __restrict__ an, const float* __restrict__ pos,
                       int* __restrict__ cnt, int* __restrict__ off,
                       float* __restrict__ dinv, float4* __restrict__ xs,
                       int* __restrict__ eidx, int n, int capx) {
    __shared__ int h[HALF];
    __shared__ int cur[HALF];
    __shared__ int wtot[2];
    __shared__ int scnt;
    __shared__ unsigned stage[STAGE_CAP];
    int bh = blockIdx.x, t = threadIdx.x;
    int b = bh >> 1, half = bh & 1;
    int cbase = b * NXC;
    int hb = cbase * capx + half * (NXC / 2) * capx;   // half's output base
    int lane = t & 63;
    if (t < HALF) h[t] = 0;
    if (t == 0) scnt = 0;
    __syncthreads();
#pragma unroll
    for (int x = 0; x < NXC; x++) {
        int rs = (cbase + x) * capx, re = gcur8[cbase + x];
        for (int k0 = rs; k0 < re; k0 += 256) {
            int k = k0 + t;
            unsigned u = 0;
            bool keep = false;
            if (k < re) {
                u = binned[k];
                keep = ((int)(u >> 24) >> 7) == half;
            }
            unsigned long long msk = __ballot(keep);
            int pre = __popcll(msk & ((1ull << lane) - 1ull));
            int cw = __popcll(msk);
            int base = 0;
            if (lane == 0 && cw) base = atomicAdd(&scnt, cw);
            base = __shfl(base, 0, 64);
            if (keep) {
                int p = base + pre;
                if (p < STAGE_CAP) stage[p] = u;
                atomicAdd(&h[(u >> 24) & (HALF - 1)], 1);
            }
        }
    }
    __syncthreads();
    // shfl exclusive scan of 128 counters (threads 0..127, 2 waves)
    int v = 0, ex = 0;
    if (t < HALF) {
        int w = t >> 6;
        v = h[t];
        int incl = v;
#pragma unroll
        for (int dd = 1; dd < 64; dd <<= 1) {
            int y = __shfl_up(incl, dd, 64);
            if (lane >= dd) incl += y;
        }
        if (lane == 63) wtot[w] = incl;
        ex = incl - v;
    }
    __syncthreads();
    if (t < HALF) {
        if (t >= 64) ex += wtot[0];
        cur[t] = ex;
        int node = (b << 8) + half * HALF + t;
        if (node < n) {
            float di = rsqrtf((float)v + 1.0f);   // +1 = self-loop
            cnt[node]  = v;
            off[node]  = hb + ex;
            dinv[node] = di;
            xs[node] = make_float4(an[node] * di, pos[3 * node] * di,
                                   pos[3 * node + 1] * di, pos[3 * node + 2] * di);
        }
    }
    __syncthreads();
    int total = scnt < STAGE_CAP ? scnt : STAGE_CAP;
    for (int k = t; k < total; k += 256) {
        unsigned u = stage[k];
        int p = atomicAdd(&cur[(u >> 24) & (HALF - 1)], 1);
        eidx[hb + p] = (int)(u & 0xFFFFFF);
    }
}

// ---------------- fused layer-1 gather + dense + z projection ------------------
// 2 threads per node: edge loop split by parity, a combined via shfl; dense
// loop redundant (weights wave-uniform -> scalar loads); even thread stores.
__global__ void k_gxz(const float4* __restrict__ xs, const int* __restrict__ eidx,
                      const int* __restrict__ off, const int* __restrict__ cnt,
                      const float* __restrict__ dinv, const float* __restrict__ W1,
                      const float* __restrict__ b1, const float* __restrict__ C,
                      uint4* __restrict__ z, int n) {
    int tid = blockIdx.x * 256 + threadIdx.x;
    int i = tid >> 1;
    int par = tid & 1;
    if (i >= n) return;
    float4 a = par ? make_float4(0.f, 0.f, 0.f, 0.f) : xs[i];   // self-loop once
    int o = off[i], c = cnt[i];
    int k = par;
    for (; k + 6 < c; k += 8) {
        int i0 = eidx[o + k],     i1 = eidx[o + k + 2];
        int i2 = eidx[o + k + 4], i3 = eidx[o + k + 6];
        float4 v0 = xs[i0], v1 = xs[i1], v2 = xs[i2], v3 = xs[i3];
        a.x += v0.x + v1.x + v2.x + v3.x;
        a.y += v0.y + v1.y + v2.y + v3.y;
        a.z += v0.z + v1.z + v2.z + v3.z;
        a.w += v0.w + v1.w + v2.w + v3.w;
    }
    for (; k < c; k += 2) {
        float4 v0 = xs[eidx[o + k]];
        a.x += v0.x; a.y += v0.y; a.z += v0.z; a.w += v0.w;
    }
    a.x += __shfl_xor(a.x, 1, 64);
    a.y += __shfl_xor(a.y, 1, 64);
    a.z += __shfl_xor(a.z, 1, 64);
    a.w += __shfl_xor(a.w, 1, 64);
    float di = dinv[i];
    float z0 = 0.f, z1 = 0.f, z2 = 0.f, z3 = 0.f,
          z4 = 0.f, z5 = 0.f, z6 = 0.f, z7 = 0.f;
#pragma unroll 4
    for (int kk = 0; kk < HID; kk++) {      // all weight indices wave-uniform
        float x1k = fmaxf(di * (a.x * W1[kk] + a.y * W1[HID + kk] +
                                a.z * W1[2 * HID + kk] + a.w * W1[3 * HID + kk])
                          + b1[kk], 0.0f);
        const float* cr = C + kk * NEXP;
        z0 += x1k * cr[0]; z1 += x1k * cr[1];
        z2 += x1k * cr[2]; z3 += x1k * cr[3];
        z4 += x1k * cr[4]; z5 += x1k * cr[5];
        z6 += x1k * cr[6]; z7 += x1k * cr[7];
    }
    if (par == 0) {
        uint4 outv;
        outv.x = packbf(z0 * di, z1 * di);
        outv.y = packbf(z2 * di, z3 * di);
        outv.z = packbf(z4 * di, z5 * di);
        outv.w = packbf(z6 * di, z7 * di);
        z[i] = outv;
    }
}

// ---------------- fused gather2 + pooling: edge-parallel 16-lane slots ---------
__global__ void k_gz(const uint4* __restrict__ z4, const int* __restrict__ eidx,
                     const int* __restrict__ off, const int* __restrict__ cnt,
                     const float* __restrict__ dinv, const int* __restrict__ batch,
                     float* __restrict__ pool, float* __restrict__ pcnt, int n) {
    int t = threadIdx.x;
    int slot = t >> 4;          // 0..15 within block
    int l = t & 15;             // lane within slot
    int i0 = blockIdx.x * (16 * NPS) + slot * NPS;
    if (i0 >= n) return;
    int i1 = i0 + NPS < n ? i0 + NPS : n;
    int rep = (blockIdx.x + slot) & (NREP - 1);
    float* rp  = pool + (size_t)rep * NGRAPH * NEXP;
    float* rpc = pcnt + (size_t)rep * NGRAPH;
    int Q = l >> 2;

    int curg = -1;
    float r0 = 0.0f, r1 = 0.0f, runlen = 0.0f;
    for (int i = i0; i < i1; i++) {
        float a0 = 0.f, a1 = 0.f, a2 = 0.f, a3 = 0.f,
              a4 = 0.f, a5 = 0.f, a6 = 0.f, a7 = 0.f;
        int o = off[i], c = cnt[i];
        for (int k = l; k < c; k += 16) {
            uint4 zr = z4[eidx[o + k]];
            a0 += bflo(zr.x); a1 += bfhi(zr.x);
            a2 += bflo(zr.y); a3 += bfhi(zr.y);
            a4 += bflo(zr.z); a5 += bfhi(zr.z);
            a6 += bflo(zr.w); a7 += bfhi(zr.w);
        }
        if (l == 0) {                        // self-loop once
            uint4 zr = z4[i];
            a0 += bflo(zr.x); a1 += bfhi(zr.x);
            a2 += bflo(zr.y); a3 += bfhi(zr.y);
            a4 += bflo(zr.z); a5 += bfhi(zr.z);
            a6 += bflo(zr.w); a7 += bfhi(zr.w);
        }
        a0 += __shfl_xor(a0, 8, 64); a1 += __shfl_xor(a1, 8, 64);
        a2 += __shfl_xor(a2, 8, 64); a3 += __shfl_xor(a3, 8, 64);
        a4 += __shfl_xor(a4, 8, 64); a5 += __shfl_xor(a5, 8, 64);
        a6 += __shfl_xor(a6, 8, 64); a7 += __shfl_xor(a7, 8, 64);
        a0 += __shfl_xor(a0, 4, 64); a1 += __shfl_xor(a1, 4, 64);
        a2 += __shfl_xor(a2, 4, 64); a3 += __shfl_xor(a3, 4, 64);
        a4 += __shfl_xor(a4, 4, 64); a5 += __shfl_xor(a5, 4, 64);
        a6 += __shfl_xor(a6, 4, 64); a7 += __shfl_xor(a7, 4, 64);
        float r0v, r1v;
        switch (Q) {
            case 0:  r0v = a0; r1v = a1; break;
            case 1:  r0v = a2; r1v = a3; break;
            case 2:  r0v = a4; r1v = a5; break;
            default: r0v = a6; r1v = a7; break;
        }
        r0v += __shfl_xor(r0v, 1, 64); r1v += __shfl_xor(r1v, 1, 64);
        r0v += __shfl_xor(r0v, 2, 64); r1v += __shfl_xor(r1v, 2, 64);
        float di = dinv[i];
        float v0 = di * r0v, v1 = di * r1v;
        int g = batch[i];
        if (g != curg) {                     // slot-uniform branch
            if (curg >= 0 && (l & 3) == 0) {
                atomicAdd(&rp[curg * NEXP + 2 * Q], r0);
                atomicAdd(&rp[curg * NEXP + 2 * Q + 1], r1);
                if (l == 0) atomicAdd(&rpc[curg], runlen);
            }
            curg = g; r0 = v0; r1 = v1; runlen = 1.0f;
        } else { r0 += v0; r1 += v1; runlen += 1.0f; }
    }
    if (curg >= 0 && (l & 3) == 0) {
        atomicAdd(&rp[curg * NEXP + 2 * Q], r0);
        atomicAdd(&rp[curg * NEXP + 2 * Q + 1], r1);
        if (l == 0) atomicAdd(&rpc[curg], runlen);
    }
}

// ---------------- replica-sum + mean + (blin + b2@Wlin) + log_softmax ----------
__global__ void k_lsm(const float* __restrict__ pool, const float* __restrict__ pcnt,
                      const float* __restrict__ blin, const float* __restrict__ bb2,
                      float* __restrict__ out) {
    int g = threadIdx.x;
    if (g >= NGRAPH) return;
    float p[NEXP];
#pragma unroll
    for (int k = 0; k < NEXP; k++) p[k] = 0.0f;
    float cg = 0.0f;
#pragma unroll
    for (int rr = 0; rr < NREP; rr++) {
#pragma unroll
        for (int k = 0; k < NEXP; k++) p[k] += pool[rr * NGRAPH * NEXP + g * NEXP + k];
        cg += pcnt[rr * NGRAPH + g];
    }
    float inv = 1.0f / fmaxf(cg, 1.0f);
    float v[NEXP], m = -1e30f;
#pragma unroll
    for (int k = 0; k < NEXP; k++) {
        v[k] = p[k] * inv + blin[k] + bb2[k];
        m = fmaxf(m, v[k]);
    }
    float s = 0.0f;
#pragma unroll
    for (int k = 0; k < NEXP; k++) s += expf(v[k] - m);
    float ls = logf(s);
#pragma unroll
    for (int k = 0; k < NEXP; k++) out[g * NEXP + k] = v[k] - m - ls;
}

extern "C" void kernel_launch(void* const* d_in, const int* in_sizes, int n_in,
                              void* d_out, int out_size, void* d_ws, size_t ws_size,
                              hipStream_t stream) {
    const float* an   = (const float*)d_in[0];
    const float* pos  = (const float*)d_in[1];
    const int*   ei   = (const int*)d_in[2];     // [2, E] flat (int32 view)
    const int*   batch= (const int*)d_in[3];
    const float* W1   = (const float*)d_in[4];
    const float* b1   = (const float*)d_in[5];
    const float* W2   = (const float*)d_in[6];
    const float* b2   = (const float*)d_in[7];
    const float* Wlin = (const float*)d_in[8];
    const float* blin = (const float*)d_in[9];
    float* out = (float*)d_out;

    const int n = in_sizes[0];
    const int e = in_sizes[2] / 2;
    const int* src = ei;
    const int* dst = ei + e;

    const int nbuck = (n + 255) >> 8;            // coarse buckets (<= MAXB)
    const int ch    = (e + EPC - 1) / EPC;       // chunks
    const int mreg  = nbuck * NXC;               // fixed-capacity regions
    const int capx  = 2 * (e / (mreg > 0 ? mreg : 1)) + 256;   // ~34 sigma slack

    // workspace layout (16B-aligned buffers first)
    char* p = (char*)d_ws;
    float4* xs    = (float4*)p;       p += sizeof(float4) * (size_t)n;
    uint4*  z     = (uint4*)p;        p += sizeof(uint4) * (size_t)n;   // bf16[8]/node
    float* C      = (float*)p;        p += sizeof(float) * HID * NEXP;
    float* bb2    = (float*)p;        p += sizeof(float) * NEXP;
    float* dinv   = (float*)p;        p += sizeof(float) * (size_t)n;
    float* pool   = (float*)p;        p += sizeof(float) * NREP * NGRAPH * NEXP;
    float* pcnt   = (float*)p;        p += sizeof(float) * NREP * NGRAPH;
    int*   cnt    = (int*)p;          p += sizeof(int) * (size_t)n;
    int*   off    = (int*)p;          p += sizeof(int) * (size_t)n;
    int*   gcur8  = (int*)p;          p += sizeof(int) * (mreg + 8);
    unsigned* binned = (unsigned*)p;  p += sizeof(unsigned) * (size_t)mreg * capx;
    int*   eidx   = (int*)p;          p += sizeof(int) * (size_t)mreg * capx;

    // init (region bases replace hist+cscan) + binning + fine sort
    const int initN = NREP * NGRAPH * NEXP + HID * NEXP + NEXP;
    const int initG = initN > mreg ? initN : mreg;
    k_init0<<<(initG + 255) / 256, 256, 0, stream>>>(pool, pcnt, W2, Wlin, b2, C,
                                                     bb2, gcur8, mreg, capx);
    k_binA<<<ch, 256, 0, stream>>>(src, dst, gcur8, binned, e, nbuck);
    k_binB<<<2 * nbuck, 256, 0, stream>>>(binned, gcur8, an, pos, cnt, off, dinv,
                                          xs, eidx, n, capx);

    // fused layer-1 gather + dense + projection to z (2 threads/node)
    k_gxz<<<(2 * n + 255) / 256, 256, 0, stream>>>(xs, eidx, off, cnt, dinv,
                                                   W1, b1, C, z, n);

    // layer 2 gather in 8-dim z-space + pooling, then log_softmax
    k_gz<<<(n + 16 * NPS - 1) / (16 * NPS), 256, 0, stream>>>(z, eidx, off, cnt, dinv,
                                                              batch, pool, pcnt, n);
    k_lsm<<<1, 64, 0, stream>>>(pool, pcnt, blin, bb2, out);
}